// Round 3
// baseline (8759.316 us; speedup 1.0000x reference)
//
#include <hip/hip_runtime.h>

typedef _Float16 half8  __attribute__((ext_vector_type(8)));
typedef _Float16 half4v __attribute__((ext_vector_type(4)));
typedef float    float4v __attribute__((ext_vector_type(4)));

#define MFMA16(a, b, c) __builtin_amdgcn_mfma_f32_16x16x32_f16((a), (b), (c), 0, 0, 0)

constexpr int BB = 256;   // batch
constexpr int LL = 512;   // encoder seq len
constexpr int DD = 64;    // input dim
constexpr int HH = 1024;  // hidden (enc == dec)
constexpr int SS = 24;    // decoder steps

// workspace layout (~17.8 MB total)
constexpr size_t OFF_X2   = 0;                          // [B][L][D] f16 (smoothed input)
constexpr size_t SZ_X2    = (size_t)BB * LL * DD * 2;
constexpr size_t OFF_HBUF = OFF_X2 + SZ_X2;             // [2][B][H] f16 h double-buffer
constexpr size_t SZ_HBUF  = (size_t)2 * BB * HH * 2;
constexpr size_t OFF_OUTP = OFF_HBUF + SZ_HBUF;         // [B][S][2] f32 pre-desmooth out
constexpr size_t SZ_OUTP  = (size_t)BB * SS * 2 * 4;
constexpr size_t OFF_BAR  = OFF_OUTP + SZ_OUTP;         // 8 group counters (stride 32 words) + grid counter
constexpr size_t SZ_BAR   = (8 * 32 + 32) * 4;
constexpr size_t OFF_ST11 = OFF_BAR + SZ_BAR;           // [B][2] f32
constexpr size_t OFF_ST12 = OFF_ST11 + 2048;            // [B][2] f32
constexpr size_t OFF_FLAG = OFF_ST12 + 2048;            // [256] u32 init-free flag barrier (NOT pre-zeroed)

template <int M, int N>
__device__ __forceinline__ void zero_acc(float4v (&a)[M][N]) {
  #pragma unroll
  for (int m = 0; m < M; ++m) {
    #pragma unroll
    for (int n = 0; n < N; ++n) {
      #pragma unroll
      for (int r = 0; r < 4; ++r) a[m][n][r] = 0.f;
    }
  }
}

// convert 8 consecutive f32 -> f16 MFMA fragment
__device__ __forceinline__ half8 ld_w8_f16(const float* p) {
  float4 f0 = *(const float4*)(p);
  float4 f1 = *(const float4*)(p + 4);
  half8 h;
  h[0] = (_Float16)f0.x; h[1] = (_Float16)f0.y; h[2] = (_Float16)f0.z; h[3] = (_Float16)f0.w;
  h[4] = (_Float16)f1.x; h[5] = (_Float16)f1.y; h[6] = (_Float16)f1.z; h[7] = (_Float16)f1.w;
  return h;
}

// Load Whh-style [3072][1024] weight slice for (hidden-slice s, K-quarter w) into
// register-resident B-fragments. B-frag layout: lane holds B[k][ncol], ncol = lane&15,
// k = (lane>>4)*8+j  => 8 consecutive K elems of W row (gate*1024 + s*32 + (n&1)*16 + lane&15).
__device__ __forceinline__ void load_W_frags(const float* __restrict__ W, int s, int w,
                                             int lane, half8 BW[6][8]) {
  const int l15 = lane & 15, lq = lane >> 4;
  #pragma unroll
  for (int n = 0; n < 6; ++n) {
    const int row = (n >> 1) * 1024 + s * 32 + (n & 1) * 16 + l15;
    const float* rp = W + (size_t)row * HH + (w << 8) + (lq << 3);
    #pragma unroll
    for (int ks = 0; ks < 8; ++ks) BW[n][ks] = ld_w8_f16(rp + ks * 32);
  }
}

// Counter barrier (monotonic, pre-zeroed counter). Agent-scope fences:
// release (L2 writeback) before arrive, acquire (cache inv) after wait.
__device__ __forceinline__ void ctr_barrier(unsigned* cnt, unsigned target) {
  __syncthreads();  // each wave's stores complete to coherence point before fence
  if (threadIdx.x == 0) {
    __threadfence();
    atomicAdd(cnt, 1u);
    while (__hip_atomic_load(cnt, __ATOMIC_RELAXED, __HIP_MEMORY_SCOPE_AGENT) < target)
      __builtin_amdgcn_s_sleep(2);
    __threadfence();
  }
  __syncthreads();
}

// Init-free grid barrier: overwrites poison, needs no pre-zeroed memory.
// Thread i of every block polls flags[i]; all 256 blocks must set val.
__device__ __forceinline__ void flag_barrier(unsigned* flags, int blk, int tid, unsigned val) {
  __syncthreads();
  if (tid == 0) {
    __threadfence();  // release all prior stores (incl. other waves', done per __syncthreads)
    __hip_atomic_store(&flags[blk], val, __ATOMIC_RELAXED, __HIP_MEMORY_SCOPE_AGENT);
  }
  while (__hip_atomic_load(&flags[tid], __ATOMIC_RELAXED, __HIP_MEMORY_SCOPE_AGENT) != val)
    __builtin_amdgcn_s_sleep(2);
  __threadfence();  // acquire
  __syncthreads();
}

// partial sums: P[wave][local_row 0..31][col 0..95(+pad)]  pitch 97
#define PS(rw, cl) (P[(rw)*97 + (cl)] + P[3104 + (rw)*97 + (cl)] + \
                    P[6208 + (rw)*97 + (cl)] + P[9312 + (rw)*97 + (cl)])

__global__ __launch_bounds__(256, 1) void ts_fused(
    const float* __restrict__ x,
    const float* __restrict__ eWih, const float* __restrict__ eWhh,
    const float* __restrict__ ebih, const float* __restrict__ ebhh,
    const float* __restrict__ dWih, const float* __restrict__ dWhh,
    const float* __restrict__ dbih, const float* __restrict__ dbhh,
    const float* __restrict__ fciW, const float* __restrict__ fcib,
    const float* __restrict__ fcW,  const float* __restrict__ fcb,
    float* __restrict__ out, char* __restrict__ ws) {
  __shared__ float P[4 * 32 * 97];  // per-wave K-partial sums (49,664 B)
  __shared__ float Q[32 * 97];      // enc: inn ; dec: gi_dec (constant over steps)

  _Float16* x2    = (_Float16*)(ws + OFF_X2);
  _Float16* hbuf  = (_Float16*)(ws + OFF_HBUF);
  float* outp     = (float*)(ws + OFF_OUTP);
  unsigned* bar   = (unsigned*)(ws + OFF_BAR);
  float* st11     = (float*)(ws + OFF_ST11);
  float* st12     = (float*)(ws + OFF_ST12);
  unsigned* flags = (unsigned*)(ws + OFF_FLAG);

  const int tid  = threadIdx.x;
  const int blk  = blockIdx.x;
  const int lane = tid & 63;
  const int w    = tid >> 6;   // wave = K-quarter
  const int l15  = lane & 15;
  const int lq   = lane >> 4;
  const int g    = blk & 7;    // batch group: rows g*32..g*32+31 (XCD-local if round-robin)
  const int s    = blk >> 3;   // hidden slice: cols s*32..s*32+31
  const int eb   = tid >> 3;   // epilogue: local batch row 0..31
  const int jq   = tid & 7;    // epilogue: j-quad, j = jq*4+e
  const int colb = s * 32 + jq * 4;

  // ---------------- phase 0: smoothing + zero-init ----------------
  if (blk < 64) {
    const int gt = blk * 256 + tid;
    const int b = gt >> 6, d = gt & 63;
    const float* xp = x + (size_t)b * LL * DD + d;
    _Float16* x2p = x2 + (size_t)b * LL * DD + d;
    float v1 = 0.f, v2 = 0.f;
    #pragma unroll 1
    for (int t = 0; t < LL; ++t) {
      float xv = xp[(size_t)t * DD];
      v1 = (t == 0) ? xv : 0.7f * xv + 0.3f * v1;   // alpha=0.3 pass
      v2 = (t == 0) ? v1 : 0.5f * v1 + 0.5f * v2;   // beta=0.5 pass
      x2p[(size_t)t * DD] = (_Float16)v2;
    }
    if (d == 1 || d == 2) { st11[b * 2 + (d - 1)] = v1; st12[b * 2 + (d - 1)] = v2; }
  } else {
    // zero hbuf (h0=0), outp, bar (incl. grid counter) — contiguous region
    unsigned* zr = (unsigned*)(ws + OFF_HBUF);
    const int NZ = (int)((SZ_HBUF + SZ_OUTP + SZ_BAR) / 4);
    for (int i = (blk - 64) * 256 + tid; i < NZ; i += 192 * 256) zr[i] = 0u;
  }

  // grid barrier #1 — init-free (counters not yet trustworthy before this point)
  flag_barrier(flags, blk, tid, 1u);

  int epoch = 0;
  unsigned* mybar   = bar + g * 32;
  unsigned* gridbar = bar + 8 * 32;

  // ---------------- encoder ----------------
  half8 BW[6][8];                       // Whh slice, register-stationary (192 VGPRs)
  load_W_frags(eWhh, s, w, lane, BW);
  half8 BWi[6][2];                      // Wih slice (K=64), wave 0 only
  if (w == 0) {
    #pragma unroll
    for (int n = 0; n < 6; ++n) {
      const int row = (n >> 1) * 1024 + s * 32 + (n & 1) * 16 + l15;
      const float* rp = eWih + (size_t)row * DD + (lq << 3);
      #pragma unroll
      for (int ks = 0; ks < 2; ++ks) BWi[n][ks] = ld_w8_f16(rp + ks * 32);
    }
  }
  float ebr[4], ebz[4], ebin[4], ebhn[4];
  #pragma unroll
  for (int e = 0; e < 4; ++e) {
    const int c = colb + e;
    ebr[e]  = ebih[c] + ebhh[c];                 // r: biases merge
    ebz[e]  = ebih[1024 + c] + ebhh[1024 + c];   // z: biases merge
    ebin[e] = ebih[2048 + c];                    // n: stays separate (r * (hn + bhh_n))
    ebhn[e] = ebhh[2048 + c];
  }
  float hold[4] = {0.f, 0.f, 0.f, 0.f};  // fp32 master h for owned (b,j) elements

  #pragma unroll 1
  for (int t = 0; t < LL; ++t) {
    const _Float16* hc = hbuf + (size_t)(t & 1) * BB * HH;
    _Float16* hnx = hbuf + (size_t)((t + 1) & 1) * BB * HH;

    float4v acc[2][6], accI[2][2];
    zero_acc(acc);
    zero_acc(accI);

    if (w == 0) {  // gi = x2_t @ Wih^T : r,z seed acc; inn kept separate in accI
      #pragma unroll
      for (int ks = 0; ks < 2; ++ks) {
        const _Float16* ap = x2 + (size_t)(g * 32 + l15) * (LL * DD) + (size_t)t * DD + ks * 32 + (lq << 3);
        half8 a0 = *(const half8*)ap;
        half8 a1 = *(const half8*)(ap + (size_t)16 * LL * DD);
        #pragma unroll
        for (int n = 0; n < 6; ++n) {
          if (n < 4) {
            acc[0][n] = MFMA16(a0, BWi[n][ks], acc[0][n]);
            acc[1][n] = MFMA16(a1, BWi[n][ks], acc[1][n]);
          } else {
            accI[0][n - 4] = MFMA16(a0, BWi[n][ks], accI[0][n - 4]);
            accI[1][n - 4] = MFMA16(a1, BWi[n][ks], accI[1][n - 4]);
          }
        }
      }
    }
    // gh partial = h_t[g-rows, K-quarter w] @ Whh^T
    #pragma unroll
    for (int ks = 0; ks < 8; ++ks) {
      const _Float16* ap = hc + (size_t)(g * 32 + l15) * HH + (w << 8) + ks * 32 + (lq << 3);
      half8 a0 = *(const half8*)ap;
      half8 a1 = *(const half8*)(ap + 16 * HH);
      #pragma unroll
      for (int n = 0; n < 6; ++n) {
        acc[0][n] = MFMA16(a0, BW[n][ks], acc[0][n]);
        acc[1][n] = MFMA16(a1, BW[n][ks], acc[1][n]);
      }
    }
    {  // partials -> LDS  (C-layout: row = m*16+lq*4+r, col = gate*32+(n&1)*16+l15)
      float* Pw = P + w * 3104;
      #pragma unroll
      for (int m = 0; m < 2; ++m) {
        const int row0 = m * 16 + lq * 4;
        #pragma unroll
        for (int n = 0; n < 6; ++n) {
          const int col = (n >> 1) * 32 + (n & 1) * 16 + l15;
          #pragma unroll
          for (int r = 0; r < 4; ++r) Pw[(row0 + r) * 97 + col] = acc[m][n][r];
        }
      }
      if (w == 0) {
        #pragma unroll
        for (int m = 0; m < 2; ++m) {
          const int row0 = m * 16 + lq * 4;
          #pragma unroll
          for (int n2 = 0; n2 < 2; ++n2) {
            const int col = n2 * 16 + l15;
            #pragma unroll
            for (int r = 0; r < 4; ++r) Q[(row0 + r) * 97 + col] = accI[m][n2][r];
          }
        }
      }
    }
    __syncthreads();
    {  // GRU epilogue, fp32
      half4v hh;
      #pragma unroll
      for (int e = 0; e < 4; ++e) {
        const int j = jq * 4 + e;
        const float Sr = PS(eb, j);        // ir+hr
        const float Sz = PS(eb, 32 + j);   // iz+hz
        const float Hn = PS(eb, 64 + j);   // hn only
        const float rr = 1.f / (1.f + __expf(-(Sr + ebr[e])));
        const float zz = 1.f / (1.f + __expf(-(Sz + ebz[e])));
        const float aN = (Q[eb * 97 + j] + ebin[e]) + rr * (Hn + ebhn[e]);
        const float nn = 1.f - 2.f / (1.f + __expf(2.f * aN));
        const float hv = (1.f - zz) * nn + zz * hold[e];
        hold[e] = hv;
        hh[e] = (_Float16)hv;
      }
      *(half4v*)(hnx + (size_t)(g * 32 + eb) * HH + s * 32 + jq * 4) = hh;
    }
    ctr_barrier(mybar, 32u * (unsigned)(++epoch));
  }

  // ---------------- D0: gi_dec = hT@dWih^T + dbih (-> Q), h0d = hT@fciW^T + fcib ----------------
  {
    const _Float16* hT = hbuf;  // parity: after 512 steps hT lives in buf0
    float4v acc[2][6];
    zero_acc(acc);
    #pragma unroll 1
    for (int ks = 0; ks < 8; ++ks) {
      const _Float16* ap = hT + (size_t)(g * 32 + l15) * HH + (w << 8) + ks * 32 + (lq << 3);
      half8 a0 = *(const half8*)ap;
      half8 a1 = *(const half8*)(ap + 16 * HH);
      #pragma unroll
      for (int n = 0; n < 6; ++n) {
        const int row = (n >> 1) * 1024 + s * 32 + (n & 1) * 16 + l15;
        half8 bf = ld_w8_f16(dWih + (size_t)row * HH + (w << 8) + ks * 32 + (lq << 3));
        acc[0][n] = MFMA16(a0, bf, acc[0][n]);
        acc[1][n] = MFMA16(a1, bf, acc[1][n]);
      }
    }
    {
      float* Pw = P + w * 3104;
      #pragma unroll
      for (int m = 0; m < 2; ++m) {
        const int row0 = m * 16 + lq * 4;
        #pragma unroll
        for (int n = 0; n < 6; ++n) {
          const int col = (n >> 1) * 32 + (n & 1) * 16 + l15;
          #pragma unroll
          for (int r = 0; r < 4; ++r) Pw[(row0 + r) * 97 + col] = acc[m][n][r];
        }
      }
    }
    __syncthreads();
    #pragma unroll
    for (int e = 0; e < 4; ++e) {   // Q <- gi_dec (+ dbih), constant for all 24 steps
      const int j = jq * 4 + e;
      #pragma unroll
      for (int gate = 0; gate < 3; ++gate) {
        const int col = gate * 32 + j;
        Q[eb * 97 + col] = PS(eb, col) + dbih[gate * 1024 + s * 32 + j];
      }
    }
    __syncthreads();
    // h0d = hT @ fciW^T + fcib
    float4v acc2[2][2];
    zero_acc(acc2);
    #pragma unroll 1
    for (int ks = 0; ks < 8; ++ks) {
      const _Float16* ap = hT + (size_t)(g * 32 + l15) * HH + (w << 8) + ks * 32 + (lq << 3);
      half8 a0 = *(const half8*)ap;
      half8 a1 = *(const half8*)(ap + 16 * HH);
      #pragma unroll
      for (int n2 = 0; n2 < 2; ++n2) {
        const int row = s * 32 + n2 * 16 + l15;
        half8 bf = ld_w8_f16(fciW + (size_t)row * HH + (w << 8) + ks * 32 + (lq << 3));
        acc2[0][n2] = MFMA16(a0, bf, acc2[0][n2]);
        acc2[1][n2] = MFMA16(a1, bf, acc2[1][n2]);
      }
    }
    {
      float* Pw = P + w * 3104;
      #pragma unroll
      for (int m = 0; m < 2; ++m) {
        const int row0 = m * 16 + lq * 4;
        #pragma unroll
        for (int n2 = 0; n2 < 2; ++n2) {
          const int col = n2 * 16 + l15;
          #pragma unroll
          for (int r = 0; r < 4; ++r) Pw[(row0 + r) * 97 + col] = acc2[m][n2][r];
        }
      }
    }
    __syncthreads();
    {
      half4v hh;
      #pragma unroll
      for (int e = 0; e < 4; ++e) {
        const int j = jq * 4 + e;
        const float v = PS(eb, j) + fcib[s * 32 + j];
        hold[e] = v;
        hh[e] = (_Float16)v;
      }
      // write h0d to buf1 (buf0 = hT still being read by group peers until barrier)
      *(half4v*)(hbuf + (size_t)BB * HH + (size_t)(g * 32 + eb) * HH + s * 32 + jq * 4) = hh;
    }
    ctr_barrier(mybar, 32u * (unsigned)(++epoch));
  }

  // ---------------- decoder ----------------
  load_W_frags(dWhh, s, w, lane, BW);  // reuse register file
  float dbr_[4], dbz_[4], dbn_[4], fw0[4], fw1[4];
  #pragma unroll
  for (int e = 0; e < 4; ++e) {
    const int c = colb + e;
    dbr_[e] = dbhh[c];
    dbz_[e] = dbhh[1024 + c];
    dbn_[e] = dbhh[2048 + c];
    fw0[e] = fcW[c];           // fc_W [2][1024]
    fw1[e] = fcW[1024 + c];
  }
  #pragma unroll 1
  for (int t = 0; t < SS; ++t) {
    const _Float16* hc = hbuf + (size_t)((t + 1) & 1) * BB * HH;  // t=0 reads buf1 (h0d)
    _Float16* hnx = hbuf + (size_t)(t & 1) * BB * HH;
    float4v acc[2][6];
    zero_acc(acc);
    #pragma unroll
    for (int ks = 0; ks < 8; ++ks) {
      const _Float16* ap = hc + (size_t)(g * 32 + l15) * HH + (w << 8) + ks * 32 + (lq << 3);
      half8 a0 = *(const half8*)ap;
      half8 a1 = *(const half8*)(ap + 16 * HH);
      #pragma unroll
      for (int n = 0; n < 6; ++n) {
        acc[0][n] = MFMA16(a0, BW[n][ks], acc[0][n]);
        acc[1][n] = MFMA16(a1, BW[n][ks], acc[1][n]);
      }
    }
    {
      float* Pw = P + w * 3104;
      #pragma unroll
      for (int m = 0; m < 2; ++m) {
        const int row0 = m * 16 + lq * 4;
        #pragma unroll
        for (int n = 0; n < 6; ++n) {
          const int col = (n >> 1) * 32 + (n & 1) * 16 + l15;
          #pragma unroll
          for (int r = 0; r < 4; ++r) Pw[(row0 + r) * 97 + col] = acc[m][n][r];
        }
      }
    }
    __syncthreads();
    {
      half4v hh;
      float p0 = 0.f, p1 = 0.f;
      #pragma unroll
      for (int e = 0; e < 4; ++e) {
        const int j = jq * 4 + e;
        const float rr = 1.f / (1.f + __expf(-(PS(eb, j) + Q[eb * 97 + j] + dbr_[e])));
        const float zz = 1.f / (1.f + __expf(-(PS(eb, 32 + j) + Q[eb * 97 + 32 + j] + dbz_[e])));
        const float aN = Q[eb * 97 + 64 + j] + rr * (PS(eb, 64 + j) + dbn_[e]);
        const float nn = 1.f - 2.f / (1.f + __expf(2.f * aN));
        const float hv = (1.f - zz) * nn + zz * hold[e];
        hold[e] = hv;
        hh[e] = (_Float16)hv;
        p0 += hv * fw0[e];
        p1 += hv * fw1[e];
      }
      *(half4v*)(hnx + (size_t)(g * 32 + eb) * HH + s * 32 + jq * 4) = hh;
      // fc fused: reduce over this CU's 32 hidden cols (8 adjacent lanes share a batch row)
      p0 += __shfl_xor(p0, 1); p0 += __shfl_xor(p0, 2); p0 += __shfl_xor(p0, 4);
      p1 += __shfl_xor(p1, 1); p1 += __shfl_xor(p1, 2); p1 += __shfl_xor(p1, 4);
      if (jq == 0) {
        atomicAdd(&outp[((g * 32 + eb) * SS + t) * 2 + 0], p0);
        atomicAdd(&outp[((g * 32 + eb) * SS + t) * 2 + 1], p1);
      }
    }
    ctr_barrier(mybar, 32u * (unsigned)(++epoch));
  }

  // grid barrier #2 (counter pre-zeroed in phase 0)
  ctr_barrier(gridbar, 256u);

  // ---------------- final: fc bias + two shifted de-smoothing passes ----------------
  if (blk < 2) {
    const int t5 = blk * 256 + tid;   // 512 threads: (b, c)
    const int b = t5 >> 1, c = t5 & 1;
    const float s2v = st12[b * 2 + c];
    const float s1v = st11[b * 2 + c];
    const float bias = fcb[c];
    float o0p = 0.f, o1p = 0.f;
    #pragma unroll 1
    for (int t = 0; t < SS; ++t) {
      const float o0 = outp[(b * SS + t) * 2 + c] + bias;
      const float o1 = 2.f * o0 - ((t == 0) ? s2v : o0p);              // (o0-0.5*st2)/0.5
      const float o2 = (o1 - 0.3f * ((t == 0) ? s1v : o1p)) * (1.f / 0.7f);
      o0p = o0; o1p = o1;
      out[b * 48 + t * 2 + c] = o2;
    }
  }

  // replay-safety: leave flags at 0 for the next launch (safe: every block has
  // passed flag-barrier #1 before any block reaches this point — guaranteed by
  // grid barrier #2)
  if (tid == 0)
    __hip_atomic_store(&flags[blk], 0u, __ATOMIC_RELAXED, __HIP_MEMORY_SCOPE_AGENT);
}

extern "C" void kernel_launch(void* const* d_in, const int* in_sizes, int n_in,
                              void* d_out, int out_size, void* d_ws, size_t ws_size,
                              hipStream_t stream) {
  (void)in_sizes; (void)n_in; (void)out_size; (void)ws_size;
  const float* x    = (const float*)d_in[0];
  const float* eWih = (const float*)d_in[1];
  const float* eWhh = (const float*)d_in[2];
  const float* ebih = (const float*)d_in[3];
  const float* ebhh = (const float*)d_in[4];
  const float* dWih = (const float*)d_in[5];
  const float* dWhh = (const float*)d_in[6];
  const float* dbih = (const float*)d_in[7];
  const float* dbhh = (const float*)d_in[8];
  const float* fciW = (const float*)d_in[9];
  const float* fcib = (const float*)d_in[10];
  const float* fcW  = (const float*)d_in[11];
  const float* fcb  = (const float*)d_in[12];
  float* out = (float*)d_out;
  char* ws = (char*)d_ws;

  ts_fused<<<dim3(256), dim3(256), 0, stream>>>(
      x, eWih, eWhh, ebih, ebhh, dWih, dWhh, dbih, dbhh,
      fciW, fcib, fcW, fcb, out, ws);
}

// Round 4
// 3998.688 us; speedup vs baseline: 2.1905x; 2.1905x over previous
//
#include <hip/hip_runtime.h>

typedef _Float16 half8  __attribute__((ext_vector_type(8)));
typedef _Float16 half4v __attribute__((ext_vector_type(4)));
typedef float    float4v __attribute__((ext_vector_type(4)));

#define MFMA16(a, b, c) __builtin_amdgcn_mfma_f32_16x16x32_f16((a), (b), (c), 0, 0, 0)

constexpr int BB = 256;   // batch
constexpr int LL = 512;   // encoder seq len
constexpr int DD = 64;    // input dim
constexpr int HH = 1024;  // hidden (enc == dec)
constexpr int SS = 24;    // decoder steps

// workspace layout (~17.8 MB total)
constexpr size_t OFF_X2   = 0;                          // [B][L][D] f16 (smoothed input)
constexpr size_t SZ_X2    = (size_t)BB * LL * DD * 2;
constexpr size_t OFF_HBUF = OFF_X2 + SZ_X2;             // [2][B][H] f16 h double-buffer
constexpr size_t SZ_HBUF  = (size_t)2 * BB * HH * 2;
constexpr size_t OFF_OUTP = OFF_HBUF + SZ_HBUF;         // [B][S][2] f32 pre-desmooth out
constexpr size_t SZ_OUTP  = (size_t)BB * SS * 2 * 4;
constexpr size_t OFF_BAR  = OFF_OUTP + SZ_OUTP;         // 8 group counters (stride 32 words) + grid counter
constexpr size_t SZ_BAR   = (8 * 32 + 32) * 4;
constexpr size_t OFF_ST11 = OFF_BAR + SZ_BAR;           // [B][2] f32
constexpr size_t OFF_ST12 = OFF_ST11 + 2048;            // [B][2] f32
constexpr size_t OFF_FLAG = OFF_ST12 + 2048;            // [256] u32 init-free flag barrier (NOT pre-zeroed)

// ---- agent-scope (cross-XCD coherent, cache-bypassing) accessors ----
// sc1 per-access coherence instead of whole-L2 wbl2/inv fences.
__device__ __forceinline__ void agstore_u64(void* p, unsigned long long v) {
  __hip_atomic_store((unsigned long long*)p, v, __ATOMIC_RELAXED, __HIP_MEMORY_SCOPE_AGENT);
}
__device__ __forceinline__ void agstore_u32(void* p, unsigned v) {
  __hip_atomic_store((unsigned*)p, v, __ATOMIC_RELAXED, __HIP_MEMORY_SCOPE_AGENT);
}
__device__ __forceinline__ half8 agload_h8(const _Float16* p) {
  const unsigned long long* q = (const unsigned long long*)p;
  union { unsigned long long u[2]; half8 h; } cv;
  cv.u[0] = __hip_atomic_load(q,     __ATOMIC_RELAXED, __HIP_MEMORY_SCOPE_AGENT);
  cv.u[1] = __hip_atomic_load(q + 1, __ATOMIC_RELAXED, __HIP_MEMORY_SCOPE_AGENT);
  return cv.h;
}
__device__ __forceinline__ void agstore_h4(void* p, half4v h) {
  union { half4v h; unsigned long long u; } cv; cv.h = h;
  agstore_u64(p, cv.u);
}

template <int M, int N>
__device__ __forceinline__ void zero_acc(float4v (&a)[M][N]) {
  #pragma unroll
  for (int m = 0; m < M; ++m) {
    #pragma unroll
    for (int n = 0; n < N; ++n) {
      #pragma unroll
      for (int r = 0; r < 4; ++r) a[m][n][r] = 0.f;
    }
  }
}

// convert 8 consecutive f32 -> f16 MFMA fragment
__device__ __forceinline__ half8 ld_w8_f16(const float* p) {
  float4 f0 = *(const float4*)(p);
  float4 f1 = *(const float4*)(p + 4);
  half8 h;
  h[0] = (_Float16)f0.x; h[1] = (_Float16)f0.y; h[2] = (_Float16)f0.z; h[3] = (_Float16)f0.w;
  h[4] = (_Float16)f1.x; h[5] = (_Float16)f1.y; h[6] = (_Float16)f1.z; h[7] = (_Float16)f1.w;
  return h;
}

// Load Whh-style [3072][1024] weight slice for (hidden-slice s, K-quarter w) into
// register-resident B-fragments. B-frag layout: lane holds B[k][ncol], ncol = lane&15,
// k = (lane>>4)*8+j  => 8 consecutive K elems of W row (gate*1024 + s*32 + (n&1)*16 + lane&15).
__device__ __forceinline__ void load_W_frags(const float* __restrict__ W, int s, int w,
                                             int lane, half8 BW[6][8]) {
  const int l15 = lane & 15, lq = lane >> 4;
  #pragma unroll
  for (int n = 0; n < 6; ++n) {
    const int row = (n >> 1) * 1024 + s * 32 + (n & 1) * 16 + l15;
    const float* rp = W + (size_t)row * HH + (w << 8) + (lq << 3);
    #pragma unroll
    for (int ks = 0; ks < 8; ++ks) BW[n][ks] = ld_w8_f16(rp + ks * 32);
  }
}

// Counter barrier (monotonic, pre-zeroed counter). NO cache-maintenance fences:
// __syncthreads drains vmcnt (write-through stores have reached the coherence
// point); arrival RMW + agent-scope polls are coherent at L3; subsequent h reads
// are agent-scope loads (bypass stale L1/L2), so no acquire-inv is needed.
__device__ __forceinline__ void ctr_barrier(unsigned* cnt, unsigned target) {
  __syncthreads();
  if (threadIdx.x == 0) {
    atomicAdd(cnt, 1u);
    while (__hip_atomic_load(cnt, __ATOMIC_RELAXED, __HIP_MEMORY_SCOPE_AGENT) < target)
      __builtin_amdgcn_s_sleep(2);
  }
  __syncthreads();
}

// Init-free grid barrier: overwrites poison, needs no pre-zeroed memory.
__device__ __forceinline__ void flag_barrier(unsigned* flags, int blk, int tid, unsigned val) {
  __syncthreads();
  if (tid == 0) agstore_u32(&flags[blk], val);
  while (__hip_atomic_load(&flags[tid], __ATOMIC_RELAXED, __HIP_MEMORY_SCOPE_AGENT) != val)
    __builtin_amdgcn_s_sleep(2);
  __syncthreads();
}

// partial sums: P[wave][local_row 0..31][col 0..95(+pad)]  pitch 97
#define PS(rw, cl) (P[(rw)*97 + (cl)] + P[3104 + (rw)*97 + (cl)] + \
                    P[6208 + (rw)*97 + (cl)] + P[9312 + (rw)*97 + (cl)])

__global__ __launch_bounds__(256, 1) void ts_fused(
    const float* __restrict__ x,
    const float* __restrict__ eWih, const float* __restrict__ eWhh,
    const float* __restrict__ ebih, const float* __restrict__ ebhh,
    const float* __restrict__ dWih, const float* __restrict__ dWhh,
    const float* __restrict__ dbih, const float* __restrict__ dbhh,
    const float* __restrict__ fciW, const float* __restrict__ fcib,
    const float* __restrict__ fcW,  const float* __restrict__ fcb,
    float* __restrict__ out, char* __restrict__ ws) {
  __shared__ float P[4 * 32 * 97];  // per-wave K-partial sums (49,664 B)
  __shared__ float Q[32 * 97];      // enc: inn ; dec: gi_dec (constant over steps)

  _Float16* x2    = (_Float16*)(ws + OFF_X2);
  _Float16* hbuf  = (_Float16*)(ws + OFF_HBUF);
  float* outp     = (float*)(ws + OFF_OUTP);
  unsigned* bar   = (unsigned*)(ws + OFF_BAR);
  float* st11     = (float*)(ws + OFF_ST11);
  float* st12     = (float*)(ws + OFF_ST12);
  unsigned* flags = (unsigned*)(ws + OFF_FLAG);

  const int tid  = threadIdx.x;
  const int blk  = blockIdx.x;
  const int lane = tid & 63;
  const int w    = tid >> 6;   // wave = K-quarter
  const int l15  = lane & 15;
  const int lq   = lane >> 4;
  const int g    = blk & 7;    // batch group: rows g*32..g*32+31
  const int s    = blk >> 3;   // hidden slice: cols s*32..s*32+31
  const int eb   = tid >> 3;   // epilogue: local batch row 0..31
  const int jq   = tid & 7;    // epilogue: j-quad, j = jq*4+e
  const int colb = s * 32 + jq * 4;

  // ---------------- phase 0: smoothing (64 blk × 64 thr × 4 chains) + zero-init ----------------
  if (blk < 64) {
    if (tid < 64) {
      const int idx = blk * 64 + tid;   // 4096 threads: (b, d-quad)
      const int b = idx >> 4, dq = idx & 15, d = dq * 4;
      const float* xp = x + (size_t)b * LL * DD + d;
      _Float16* x2p = x2 + (size_t)b * LL * DD + d;
      float v1[4] = {0.f, 0.f, 0.f, 0.f}, v2[4] = {0.f, 0.f, 0.f, 0.f};
      #pragma unroll 1
      for (int t = 0; t < LL; ++t) {
        const float4 xv = *(const float4*)(xp + (size_t)t * DD);
        const float xe[4] = {xv.x, xv.y, xv.z, xv.w};
        half4v hv;
        #pragma unroll
        for (int e = 0; e < 4; ++e) {
          v1[e] = (t == 0) ? xe[e] : 0.7f * xe[e] + 0.3f * v1[e];  // alpha=0.3 pass
          v2[e] = (t == 0) ? v1[e] : 0.5f * v1[e] + 0.5f * v2[e];  // beta=0.5 pass
          hv[e] = (_Float16)v2[e];
        }
        agstore_h4(x2p + (size_t)t * DD, hv);  // write-through (cross-XCD read later)
      }
      if (dq == 0) {  // COLS = {1,2}
        union { float f[2]; unsigned long long u; } c1, c2;
        c1.f[0] = v1[1]; c1.f[1] = v1[2];
        c2.f[0] = v2[1]; c2.f[1] = v2[2];
        agstore_u64(&st11[b * 2], c1.u);
        agstore_u64(&st12[b * 2], c2.u);
      }
    }
  } else {
    // zero hbuf (h0=0), outp, bar (incl. grid counter) — write-through
    unsigned long long* zr = (unsigned long long*)(ws + OFF_HBUF);
    const int NZ = (int)((SZ_HBUF + SZ_OUTP + SZ_BAR) / 8);
    for (int i = (blk - 64) * 256 + tid; i < NZ; i += 192 * 256) agstore_u64(&zr[i], 0ull);
  }

  // grid barrier #1 — init-free
  flag_barrier(flags, blk, tid, 1u);

  int epoch = 0;
  unsigned* mybar   = bar + g * 32;
  unsigned* gridbar = bar + 8 * 32;

  // ---------------- encoder ----------------
  half8 BW[6][8];                       // Whh slice, register-stationary (192 VGPRs)
  load_W_frags(eWhh, s, w, lane, BW);
  half8 BWi[6][2];                      // Wih slice (K=64), wave 0 only
  if (w == 0) {
    #pragma unroll
    for (int n = 0; n < 6; ++n) {
      const int row = (n >> 1) * 1024 + s * 32 + (n & 1) * 16 + l15;
      const float* rp = eWih + (size_t)row * DD + (lq << 3);
      #pragma unroll
      for (int ks = 0; ks < 2; ++ks) BWi[n][ks] = ld_w8_f16(rp + ks * 32);
    }
  }
  float ebr[4], ebz[4], ebin[4], ebhn[4];
  #pragma unroll
  for (int e = 0; e < 4; ++e) {
    const int c = colb + e;
    ebr[e]  = ebih[c] + ebhh[c];                 // r: biases merge
    ebz[e]  = ebih[1024 + c] + ebhh[1024 + c];   // z: biases merge
    ebin[e] = ebih[2048 + c];                    // n: stays separate (r * (hn + bhh_n))
    ebhn[e] = ebhh[2048 + c];
  }
  float hold[4] = {0.f, 0.f, 0.f, 0.f};  // fp32 master h for owned (b,j) elements

  #pragma unroll 1
  for (int t = 0; t < LL; ++t) {
    const _Float16* hc = hbuf + (size_t)(t & 1) * BB * HH;
    _Float16* hnx = hbuf + (size_t)((t + 1) & 1) * BB * HH;

    float4v acc[2][6], accI[2][2];
    zero_acc(acc);
    zero_acc(accI);

    if (w == 0) {  // gi = x2_t @ Wih^T : r,z seed acc; inn kept separate in accI
      #pragma unroll
      for (int ks = 0; ks < 2; ++ks) {
        const _Float16* ap = x2 + (size_t)(g * 32 + l15) * (LL * DD) + (size_t)t * DD + ks * 32 + (lq << 3);
        half8 a0 = *(const half8*)ap;                        // write-once data: plain load safe
        half8 a1 = *(const half8*)(ap + (size_t)16 * LL * DD);
        #pragma unroll
        for (int n = 0; n < 6; ++n) {
          if (n < 4) {
            acc[0][n] = MFMA16(a0, BWi[n][ks], acc[0][n]);
            acc[1][n] = MFMA16(a1, BWi[n][ks], acc[1][n]);
          } else {
            accI[0][n - 4] = MFMA16(a0, BWi[n][ks], accI[0][n - 4]);
            accI[1][n - 4] = MFMA16(a1, BWi[n][ks], accI[1][n - 4]);
          }
        }
      }
    }
    // gh partial = h_t[g-rows, K-quarter w] @ Whh^T  (h: agent loads — rewritten data)
    #pragma unroll
    for (int ks = 0; ks < 8; ++ks) {
      const _Float16* ap = hc + (size_t)(g * 32 + l15) * HH + (w << 8) + ks * 32 + (lq << 3);
      half8 a0 = agload_h8(ap);
      half8 a1 = agload_h8(ap + 16 * HH);
      #pragma unroll
      for (int n = 0; n < 6; ++n) {
        acc[0][n] = MFMA16(a0, BW[n][ks], acc[0][n]);
        acc[1][n] = MFMA16(a1, BW[n][ks], acc[1][n]);
      }
    }
    {  // partials -> LDS  (C-layout: row = m*16+lq*4+r, col = gate*32+(n&1)*16+l15)
      float* Pw = P + w * 3104;
      #pragma unroll
      for (int m = 0; m < 2; ++m) {
        const int row0 = m * 16 + lq * 4;
        #pragma unroll
        for (int n = 0; n < 6; ++n) {
          const int col = (n >> 1) * 32 + (n & 1) * 16 + l15;
          #pragma unroll
          for (int r = 0; r < 4; ++r) Pw[(row0 + r) * 97 + col] = acc[m][n][r];
        }
      }
      if (w == 0) {
        #pragma unroll
        for (int m = 0; m < 2; ++m) {
          const int row0 = m * 16 + lq * 4;
          #pragma unroll
          for (int n2 = 0; n2 < 2; ++n2) {
            const int col = n2 * 16 + l15;
            #pragma unroll
            for (int r = 0; r < 4; ++r) Q[(row0 + r) * 97 + col] = accI[m][n2][r];
          }
        }
      }
    }
    __syncthreads();
    {  // GRU epilogue, fp32
      half4v hh;
      #pragma unroll
      for (int e = 0; e < 4; ++e) {
        const int j = jq * 4 + e;
        const float Sr = PS(eb, j);        // ir+hr
        const float Sz = PS(eb, 32 + j);   // iz+hz
        const float Hn = PS(eb, 64 + j);   // hn only
        const float rr = 1.f / (1.f + __expf(-(Sr + ebr[e])));
        const float zz = 1.f / (1.f + __expf(-(Sz + ebz[e])));
        const float aN = (Q[eb * 97 + j] + ebin[e]) + rr * (Hn + ebhn[e]);
        const float nn = 1.f - 2.f / (1.f + __expf(2.f * aN));
        const float hv = (1.f - zz) * nn + zz * hold[e];
        hold[e] = hv;
        hh[e] = (_Float16)hv;
      }
      agstore_h4(hnx + (size_t)(g * 32 + eb) * HH + s * 32 + jq * 4, hh);
    }
    ctr_barrier(mybar, 32u * (unsigned)(++epoch));
  }

  // ---------------- D0: gi_dec = hT@dWih^T + dbih (-> Q), h0d = hT@fciW^T + fcib ----------------
  {
    const _Float16* hT = hbuf;  // parity: after 512 steps hT lives in buf0
    float4v acc[2][6];
    zero_acc(acc);
    #pragma unroll 1
    for (int ks = 0; ks < 8; ++ks) {
      const _Float16* ap = hT + (size_t)(g * 32 + l15) * HH + (w << 8) + ks * 32 + (lq << 3);
      half8 a0 = agload_h8(ap);
      half8 a1 = agload_h8(ap + 16 * HH);
      #pragma unroll
      for (int n = 0; n < 6; ++n) {
        const int row = (n >> 1) * 1024 + s * 32 + (n & 1) * 16 + l15;
        half8 bf = ld_w8_f16(dWih + (size_t)row * HH + (w << 8) + ks * 32 + (lq << 3));
        acc[0][n] = MFMA16(a0, bf, acc[0][n]);
        acc[1][n] = MFMA16(a1, bf, acc[1][n]);
      }
    }
    {
      float* Pw = P + w * 3104;
      #pragma unroll
      for (int m = 0; m < 2; ++m) {
        const int row0 = m * 16 + lq * 4;
        #pragma unroll
        for (int n = 0; n < 6; ++n) {
          const int col = (n >> 1) * 32 + (n & 1) * 16 + l15;
          #pragma unroll
          for (int r = 0; r < 4; ++r) Pw[(row0 + r) * 97 + col] = acc[m][n][r];
        }
      }
    }
    __syncthreads();
    #pragma unroll
    for (int e = 0; e < 4; ++e) {   // Q <- gi_dec (+ dbih), constant for all 24 steps
      const int j = jq * 4 + e;
      #pragma unroll
      for (int gate = 0; gate < 3; ++gate) {
        const int col = gate * 32 + j;
        Q[eb * 97 + col] = PS(eb, col) + dbih[gate * 1024 + s * 32 + j];
      }
    }
    __syncthreads();
    // h0d = hT @ fciW^T + fcib
    float4v acc2[2][2];
    zero_acc(acc2);
    #pragma unroll 1
    for (int ks = 0; ks < 8; ++ks) {
      const _Float16* ap = hT + (size_t)(g * 32 + l15) * HH + (w << 8) + ks * 32 + (lq << 3);
      half8 a0 = agload_h8(ap);
      half8 a1 = agload_h8(ap + 16 * HH);
      #pragma unroll
      for (int n2 = 0; n2 < 2; ++n2) {
        const int row = s * 32 + n2 * 16 + l15;
        half8 bf = ld_w8_f16(fciW + (size_t)row * HH + (w << 8) + ks * 32 + (lq << 3));
        acc2[0][n2] = MFMA16(a0, bf, acc2[0][n2]);
        acc2[1][n2] = MFMA16(a1, bf, acc2[1][n2]);
      }
    }
    {
      float* Pw = P + w * 3104;
      #pragma unroll
      for (int m = 0; m < 2; ++m) {
        const int row0 = m * 16 + lq * 4;
        #pragma unroll
        for (int n2 = 0; n2 < 2; ++n2) {
          const int col = n2 * 16 + l15;
          #pragma unroll
          for (int r = 0; r < 4; ++r) Pw[(row0 + r) * 97 + col] = acc2[m][n2][r];
        }
      }
    }
    __syncthreads();
    {
      half4v hh;
      #pragma unroll
      for (int e = 0; e < 4; ++e) {
        const int j = jq * 4 + e;
        const float v = PS(eb, j) + fcib[s * 32 + j];
        hold[e] = v;
        hh[e] = (_Float16)v;
      }
      // write h0d to buf1 (buf0 = hT still being read by group peers until barrier)
      agstore_h4(hbuf + (size_t)BB * HH + (size_t)(g * 32 + eb) * HH + s * 32 + jq * 4, hh);
    }
    ctr_barrier(mybar, 32u * (unsigned)(++epoch));
  }

  // ---------------- decoder ----------------
  load_W_frags(dWhh, s, w, lane, BW);  // reuse register file
  float dbr_[4], dbz_[4], dbn_[4], fw0[4], fw1[4];
  #pragma unroll
  for (int e = 0; e < 4; ++e) {
    const int c = colb + e;
    dbr_[e] = dbhh[c];
    dbz_[e] = dbhh[1024 + c];
    dbn_[e] = dbhh[2048 + c];
    fw0[e] = fcW[c];           // fc_W [2][1024]
    fw1[e] = fcW[1024 + c];
  }
  #pragma unroll 1
  for (int t = 0; t < SS; ++t) {
    const _Float16* hc = hbuf + (size_t)((t + 1) & 1) * BB * HH;  // t=0 reads buf1 (h0d)
    _Float16* hnx = hbuf + (size_t)(t & 1) * BB * HH;
    float4v acc[2][6];
    zero_acc(acc);
    #pragma unroll
    for (int ks = 0; ks < 8; ++ks) {
      const _Float16* ap = hc + (size_t)(g * 32 + l15) * HH + (w << 8) + ks * 32 + (lq << 3);
      half8 a0 = agload_h8(ap);
      half8 a1 = agload_h8(ap + 16 * HH);
      #pragma unroll
      for (int n = 0; n < 6; ++n) {
        acc[0][n] = MFMA16(a0, BW[n][ks], acc[0][n]);
        acc[1][n] = MFMA16(a1, BW[n][ks], acc[1][n]);
      }
    }
    {
      float* Pw = P + w * 3104;
      #pragma unroll
      for (int m = 0; m < 2; ++m) {
        const int row0 = m * 16 + lq * 4;
        #pragma unroll
        for (int n = 0; n < 6; ++n) {
          const int col = (n >> 1) * 32 + (n & 1) * 16 + l15;
          #pragma unroll
          for (int r = 0; r < 4; ++r) Pw[(row0 + r) * 97 + col] = acc[m][n][r];
        }
      }
    }
    __syncthreads();
    {
      half4v hh;
      float p0 = 0.f, p1 = 0.f;
      #pragma unroll
      for (int e = 0; e < 4; ++e) {
        const int j = jq * 4 + e;
        const float rr = 1.f / (1.f + __expf(-(PS(eb, j) + Q[eb * 97 + j] + dbr_[e])));
        const float zz = 1.f / (1.f + __expf(-(PS(eb, 32 + j) + Q[eb * 97 + 32 + j] + dbz_[e])));
        const float aN = Q[eb * 97 + 64 + j] + rr * (PS(eb, 64 + j) + dbn_[e]);
        const float nn = 1.f - 2.f / (1.f + __expf(2.f * aN));
        const float hv = (1.f - zz) * nn + zz * hold[e];
        hold[e] = hv;
        hh[e] = (_Float16)hv;
        p0 += hv * fw0[e];
        p1 += hv * fw1[e];
      }
      agstore_h4(hnx + (size_t)(g * 32 + eb) * HH + s * 32 + jq * 4, hh);
      // fc fused: reduce over this CU's 32 hidden cols (8 adjacent lanes share a batch row)
      p0 += __shfl_xor(p0, 1); p0 += __shfl_xor(p0, 2); p0 += __shfl_xor(p0, 4);
      p1 += __shfl_xor(p1, 1); p1 += __shfl_xor(p1, 2); p1 += __shfl_xor(p1, 4);
      if (jq == 0) {
        atomicAdd(&outp[((g * 32 + eb) * SS + t) * 2 + 0], p0);
        atomicAdd(&outp[((g * 32 + eb) * SS + t) * 2 + 1], p1);
      }
    }
    ctr_barrier(mybar, 32u * (unsigned)(++epoch));
  }

  // grid barrier #2 (counter pre-zeroed in phase 0)
  ctr_barrier(gridbar, 256u);

  // ---------------- final: fc bias + two shifted de-smoothing passes ----------------
  if (blk < 2) {
    const int t5 = blk * 256 + tid;   // 512 threads: (b, c)
    const int b = t5 >> 1, c = t5 & 1;
    const float s2v = st12[b * 2 + c];
    const float s1v = st11[b * 2 + c];
    const float bias = fcb[c];
    float o0p = 0.f, o1p = 0.f;
    #pragma unroll 1
    for (int t = 0; t < SS; ++t) {
      const float o0 = outp[(b * SS + t) * 2 + c] + bias;
      const float o1 = 2.f * o0 - ((t == 0) ? s2v : o0p);              // (o0-0.5*st2)/0.5
      const float o2 = (o1 - 0.3f * ((t == 0) ? s1v : o1p)) * (1.f / 0.7f);
      o0p = o0; o1p = o1;
      out[b * 48 + t * 2 + c] = o2;
    }
  }

  // replay-safety: leave flags at 0 for the next launch (all blocks have passed
  // flag-barrier #1 before any block reaches here — guaranteed by grid barrier #2)
  if (tid == 0) agstore_u32(&flags[blk], 0u);
}

extern "C" void kernel_launch(void* const* d_in, const int* in_sizes, int n_in,
                              void* d_out, int out_size, void* d_ws, size_t ws_size,
                              hipStream_t stream) {
  (void)in_sizes; (void)n_in; (void)out_size; (void)ws_size;
  const float* x    = (const float*)d_in[0];
  const float* eWih = (const float*)d_in[1];
  const float* eWhh = (const float*)d_in[2];
  const float* ebih = (const float*)d_in[3];
  const float* ebhh = (const float*)d_in[4];
  const float* dWih = (const float*)d_in[5];
  const float* dWhh = (const float*)d_in[6];
  const float* dbih = (const float*)d_in[7];
  const float* dbhh = (const float*)d_in[8];
  const float* fciW = (const float*)d_in[9];
  const float* fcib = (const float*)d_in[10];
  const float* fcW  = (const float*)d_in[11];
  const float* fcb  = (const float*)d_in[12];
  float* out = (float*)d_out;
  char* ws = (char*)d_ws;

  ts_fused<<<dim3(256), dim3(256), 0, stream>>>(
      x, eWih, eWhh, ebih, ebhh, dWih, dWhh, dbih, dbhh,
      fciW, fcib, fcW, fcb, out, ws);
}

// Round 5
// 3666.718 us; speedup vs baseline: 2.3889x; 1.0905x over previous
//
#include <hip/hip_runtime.h>

typedef _Float16 half8  __attribute__((ext_vector_type(8)));
typedef _Float16 half4v __attribute__((ext_vector_type(4)));
typedef float    float4v __attribute__((ext_vector_type(4)));

#define MFMA16(a, b, c) __builtin_amdgcn_mfma_f32_16x16x32_f16((a), (b), (c), 0, 0, 0)

constexpr int BB = 256;   // batch
constexpr int LL = 512;   // encoder seq len
constexpr int DD = 64;    // input dim
constexpr int HH = 1024;  // hidden (enc == dec)
constexpr int SS = 24;    // decoder steps

// workspace layout (~17.8 MB total)
constexpr size_t OFF_X2    = 0;                          // [B][L][D] f16 (smoothed input)
constexpr size_t SZ_X2     = (size_t)BB * LL * DD * 2;
constexpr size_t OFF_HBUF  = OFF_X2 + SZ_X2;             // [2][B][H] f16 h double-buffer
constexpr size_t SZ_HBUF   = (size_t)2 * BB * HH * 2;
constexpr size_t OFF_OUTP  = OFF_HBUF + SZ_HBUF;         // [B][S][2] f32 pre-desmooth out
constexpr size_t SZ_OUTP   = (size_t)BB * SS * 2 * 4;
constexpr size_t OFF_BAR   = OFF_OUTP + SZ_OUTP;         // grid leader counter
constexpr size_t SZ_BAR    = 32 * 4;
constexpr size_t OFF_EFLAG = OFF_BAR + SZ_BAR;           // 8 groups × 32 epoch flags, 64B stride
constexpr size_t SZ_EFLAG  = (size_t)8 * 32 * 16 * 4;
constexpr size_t OFF_ST11  = OFF_EFLAG + SZ_EFLAG;       // [B][2] f32
constexpr size_t OFF_ST12  = OFF_ST11 + 2048;            // [B][2] f32
constexpr size_t OFF_FLAG  = OFF_ST12 + 2048;            // [256] u32 init-free flag barrier (NOT pre-zeroed)

// ---- agent-scope (cross-XCD coherent, cache-bypassing) accessors ----
__device__ __forceinline__ void agstore_u64(void* p, unsigned long long v) {
  __hip_atomic_store((unsigned long long*)p, v, __ATOMIC_RELAXED, __HIP_MEMORY_SCOPE_AGENT);
}
__device__ __forceinline__ void agstore_u32(void* p, unsigned v) {
  __hip_atomic_store((unsigned*)p, v, __ATOMIC_RELAXED, __HIP_MEMORY_SCOPE_AGENT);
}
__device__ __forceinline__ unsigned agload_u32(const unsigned* p) {
  return __hip_atomic_load(p, __ATOMIC_RELAXED, __HIP_MEMORY_SCOPE_AGENT);
}
__device__ __forceinline__ half8 agload_h8(const _Float16* p) {
  const unsigned long long* q = (const unsigned long long*)p;
  union { unsigned long long u[2]; half8 h; } cv;
  cv.u[0] = __hip_atomic_load(q,     __ATOMIC_RELAXED, __HIP_MEMORY_SCOPE_AGENT);
  cv.u[1] = __hip_atomic_load(q + 1, __ATOMIC_RELAXED, __HIP_MEMORY_SCOPE_AGENT);
  return cv.h;
}
__device__ __forceinline__ void agstore_h4(void* p, half4v h) {
  union { half4v h; unsigned long long u; } cv; cv.h = h;
  agstore_u64(p, cv.u);
}

template <int M, int N>
__device__ __forceinline__ void zero_acc(float4v (&a)[M][N]) {
  #pragma unroll
  for (int m = 0; m < M; ++m) {
    #pragma unroll
    for (int n = 0; n < N; ++n) {
      #pragma unroll
      for (int r = 0; r < 4; ++r) a[m][n][r] = 0.f;
    }
  }
}

// convert 8 consecutive f32 -> f16 MFMA fragment
__device__ __forceinline__ half8 ld_w8_f16(const float* p) {
  float4 f0 = *(const float4*)(p);
  float4 f1 = *(const float4*)(p + 4);
  half8 h;
  h[0] = (_Float16)f0.x; h[1] = (_Float16)f0.y; h[2] = (_Float16)f0.z; h[3] = (_Float16)f0.w;
  h[4] = (_Float16)f1.x; h[5] = (_Float16)f1.y; h[6] = (_Float16)f1.z; h[7] = (_Float16)f1.w;
  return h;
}

// Load Whh-style [3072][1024] weight slice for (hidden-slice s, K-quarter w) into
// register-resident B-fragments (layout: lane holds B[k][ncol], ncol=lane&15, k=(lane>>4)*8+j).
__device__ __forceinline__ void load_W_frags(const float* __restrict__ W, int s, int w,
                                             int lane, half8 BW[6][8]) {
  const int l15 = lane & 15, lq = lane >> 4;
  #pragma unroll
  for (int n = 0; n < 6; ++n) {
    const int row = (n >> 1) * 1024 + s * 32 + (n & 1) * 16 + l15;
    const float* rp = W + (size_t)row * HH + (w << 8) + (lq << 3);
    #pragma unroll
    for (int ks = 0; ks < 8; ++ks) BW[n][ks] = ld_w8_f16(rp + ks * 32);
  }
}

// ---- all-to-all epoch-flag group barrier (no RMW contention) ----
// arrive: after syncthreads (all waves' agent stores drained to coherence point),
// block stores its own epoch flag — one store, private 64B line.
__device__ __forceinline__ void bar_arrive(unsigned* ef, int lb, unsigned ep1) {
  __syncthreads();
  if (threadIdx.x == 0) agstore_u32(&ef[lb * 16], ep1);
}
// wait: lanes 0..31 of wave 0 poll all 32 group flags with ONE vector load per
// iteration; per-lane exit via exec-mask until all >= ep.
__device__ __forceinline__ void bar_wait(unsigned* ef, unsigned ep) {
  if (threadIdx.x < 32) {
    while (agload_u32(&ef[threadIdx.x * 16]) < ep)
      __builtin_amdgcn_s_sleep(1);
  }
  __syncthreads();
}

// Init-free grid barrier: overwrites poison, needs no pre-zeroed memory.
__device__ __forceinline__ void flag_barrier(unsigned* flags, int blk, int tid, unsigned val) {
  __syncthreads();
  if (tid == 0) agstore_u32(&flags[blk], val);
  while (agload_u32(&flags[tid]) != val)
    __builtin_amdgcn_s_sleep(2);
  __syncthreads();
}

// partial sums: P[wave][local_row 0..31][col 0..95(+pad)]  pitch 97
#define PS(rw, cl) (P[(rw)*97 + (cl)] + P[3104 + (rw)*97 + (cl)] + \
                    P[6208 + (rw)*97 + (cl)] + P[9312 + (rw)*97 + (cl)])

__global__ __launch_bounds__(256, 1) void ts_fused(
    const float* __restrict__ x,
    const float* __restrict__ eWih, const float* __restrict__ eWhh,
    const float* __restrict__ ebih, const float* __restrict__ ebhh,
    const float* __restrict__ dWih, const float* __restrict__ dWhh,
    const float* __restrict__ dbih, const float* __restrict__ dbhh,
    const float* __restrict__ fciW, const float* __restrict__ fcib,
    const float* __restrict__ fcW,  const float* __restrict__ fcb,
    float* __restrict__ out, char* __restrict__ ws) {
  __shared__ float P[4 * 32 * 97];  // per-wave K-partial sums (49,664 B)
  __shared__ float Q[32 * 97];      // enc: inn ; dec: gi_dec (constant over steps)

  _Float16* x2     = (_Float16*)(ws + OFF_X2);
  _Float16* hbuf   = (_Float16*)(ws + OFF_HBUF);
  float* outp      = (float*)(ws + OFF_OUTP);
  unsigned* bar    = (unsigned*)(ws + OFF_BAR);
  unsigned* eflags = (unsigned*)(ws + OFF_EFLAG);
  float* st11      = (float*)(ws + OFF_ST11);
  float* st12      = (float*)(ws + OFF_ST12);
  unsigned* flags  = (unsigned*)(ws + OFF_FLAG);

  const int tid  = threadIdx.x;
  const int blk  = blockIdx.x;
  const int lane = tid & 63;
  const int w    = tid >> 6;   // wave = K-quarter
  const int l15  = lane & 15;
  const int lq   = lane >> 4;
  const int g    = blk & 7;    // batch group: rows g*32..g*32+31
  const int s    = blk >> 3;   // hidden slice: cols s*32..s*32+31 (also local-block id in group)
  const int eb   = tid >> 3;   // epilogue: local batch row 0..31
  const int jq   = tid & 7;    // epilogue: j-quad, j = jq*4+e
  const int colb = s * 32 + jq * 4;

  // ---------------- phase 0: smoothing (64 blk × 64 thr × 4 chains) + zero-init ----------------
  if (blk < 64) {
    if (tid < 64) {
      const int idx = blk * 64 + tid;   // 4096 threads: (b, d-quad)
      const int b = idx >> 4, dq = idx & 15, d = dq * 4;
      const float* xp = x + (size_t)b * LL * DD + d;
      _Float16* x2p = x2 + (size_t)b * LL * DD + d;
      float v1[4] = {0.f, 0.f, 0.f, 0.f}, v2[4] = {0.f, 0.f, 0.f, 0.f};
      #pragma unroll 1
      for (int t = 0; t < LL; ++t) {
        const float4 xv = *(const float4*)(xp + (size_t)t * DD);
        const float xe[4] = {xv.x, xv.y, xv.z, xv.w};
        half4v hv;
        #pragma unroll
        for (int e = 0; e < 4; ++e) {
          v1[e] = (t == 0) ? xe[e] : 0.7f * xe[e] + 0.3f * v1[e];  // alpha=0.3 pass
          v2[e] = (t == 0) ? v1[e] : 0.5f * v1[e] + 0.5f * v2[e];  // beta=0.5 pass
          hv[e] = (_Float16)v2[e];
        }
        agstore_h4(x2p + (size_t)t * DD, hv);  // write-through (cross-XCD read later)
      }
      if (dq == 0) {  // COLS = {1,2}
        union { float f[2]; unsigned long long u; } c1, c2;
        c1.f[0] = v1[1]; c1.f[1] = v1[2];
        c2.f[0] = v2[1]; c2.f[1] = v2[2];
        agstore_u64(&st11[b * 2], c1.u);
        agstore_u64(&st12[b * 2], c2.u);
      }
    }
  } else {
    // zero hbuf (h0=0), outp, bar, eflags — contiguous region, write-through
    unsigned long long* zr = (unsigned long long*)(ws + OFF_HBUF);
    const int NZ = (int)((SZ_HBUF + SZ_OUTP + SZ_BAR + SZ_EFLAG) / 8);
    for (int i = (blk - 64) * 256 + tid; i < NZ; i += 192 * 256) agstore_u64(&zr[i], 0ull);
  }

  // grid barrier #1 — init-free
  flag_barrier(flags, blk, tid, 1u);

  unsigned* ef      = eflags + g * 32 * 16;  // this group's 32 epoch flags
  unsigned* gridbar = bar;

  // ---------------- encoder ----------------
  half8 BW[6][8];                       // Whh slice, register-stationary (192 VGPRs)
  load_W_frags(eWhh, s, w, lane, BW);
  half8 BWi[6][2];                      // Wih slice (K=64), wave 0 only
  if (w == 0) {
    #pragma unroll
    for (int n = 0; n < 6; ++n) {
      const int row = (n >> 1) * 1024 + s * 32 + (n & 1) * 16 + l15;
      const float* rp = eWih + (size_t)row * DD + (lq << 3);
      #pragma unroll
      for (int ks = 0; ks < 2; ++ks) BWi[n][ks] = ld_w8_f16(rp + ks * 32);
    }
  }
  float ebr[4], ebz[4], ebin[4], ebhn[4];
  #pragma unroll
  for (int e = 0; e < 4; ++e) {
    const int c = colb + e;
    ebr[e]  = ebih[c] + ebhh[c];                 // r: biases merge
    ebz[e]  = ebih[1024 + c] + ebhh[1024 + c];   // z: biases merge
    ebin[e] = ebih[2048 + c];                    // n: stays separate (r * (hn + bhh_n))
    ebhn[e] = ebhh[2048 + c];
  }
  float hold[4] = {0.f, 0.f, 0.f, 0.f};  // fp32 master h for owned (b,j) elements

  #pragma unroll 1
  for (int t = 0; t < LL; ++t) {
    const _Float16* hc = hbuf + (size_t)(t & 1) * BB * HH;
    _Float16* hnx = hbuf + (size_t)((t + 1) & 1) * BB * HH;

    float4v acc[2][6], accI[2][2];
    zero_acc(acc);
    zero_acc(accI);

    if (w == 0) {  // gi = x2_t @ Wih^T : r,z seed acc; inn kept separate in accI
      #pragma unroll
      for (int ks = 0; ks < 2; ++ks) {
        const _Float16* ap = x2 + (size_t)(g * 32 + l15) * (LL * DD) + (size_t)t * DD + ks * 32 + (lq << 3);
        half8 a0 = *(const half8*)ap;                        // write-once data: plain load safe
        half8 a1 = *(const half8*)(ap + (size_t)16 * LL * DD);
        #pragma unroll
        for (int n = 0; n < 6; ++n) {
          if (n < 4) {
            acc[0][n] = MFMA16(a0, BWi[n][ks], acc[0][n]);
            acc[1][n] = MFMA16(a1, BWi[n][ks], acc[1][n]);
          } else {
            accI[0][n - 4] = MFMA16(a0, BWi[n][ks], accI[0][n - 4]);
            accI[1][n - 4] = MFMA16(a1, BWi[n][ks], accI[1][n - 4]);
          }
        }
      }
    }
    // wait for h_t (epoch t); t=0: h0 ready via grid barrier #1
    if (t > 0) bar_wait(ef, (unsigned)t);
    // gh partial = h_t[g-rows, K-quarter w] @ Whh^T  (h: agent loads — rewritten data)
    #pragma unroll
    for (int ks = 0; ks < 8; ++ks) {
      const _Float16* ap = hc + (size_t)(g * 32 + l15) * HH + (w << 8) + ks * 32 + (lq << 3);
      half8 a0 = agload_h8(ap);
      half8 a1 = agload_h8(ap + 16 * HH);
      #pragma unroll
      for (int n = 0; n < 6; ++n) {
        acc[0][n] = MFMA16(a0, BW[n][ks], acc[0][n]);
        acc[1][n] = MFMA16(a1, BW[n][ks], acc[1][n]);
      }
    }
    {  // partials -> LDS  (C-layout: row = m*16+lq*4+r, col = gate*32+(n&1)*16+l15)
      float* Pw = P + w * 3104;
      #pragma unroll
      for (int m = 0; m < 2; ++m) {
        const int row0 = m * 16 + lq * 4;
        #pragma unroll
        for (int n = 0; n < 6; ++n) {
          const int col = (n >> 1) * 32 + (n & 1) * 16 + l15;
          #pragma unroll
          for (int r = 0; r < 4; ++r) Pw[(row0 + r) * 97 + col] = acc[m][n][r];
        }
      }
      if (w == 0) {
        #pragma unroll
        for (int m = 0; m < 2; ++m) {
          const int row0 = m * 16 + lq * 4;
          #pragma unroll
          for (int n2 = 0; n2 < 2; ++n2) {
            const int col = n2 * 16 + l15;
            #pragma unroll
            for (int r = 0; r < 4; ++r) Q[(row0 + r) * 97 + col] = accI[m][n2][r];
          }
        }
      }
    }
    __syncthreads();
    {  // GRU epilogue, fp32
      half4v hh;
      #pragma unroll
      for (int e = 0; e < 4; ++e) {
        const int j = jq * 4 + e;
        const float Sr = PS(eb, j);        // ir+hr
        const float Sz = PS(eb, 32 + j);   // iz+hz
        const float Hn = PS(eb, 64 + j);   // hn only
        const float rr = 1.f / (1.f + __expf(-(Sr + ebr[e])));
        const float zz = 1.f / (1.f + __expf(-(Sz + ebz[e])));
        const float aN = (Q[eb * 97 + j] + ebin[e]) + rr * (Hn + ebhn[e]);
        const float nn = 1.f - 2.f / (1.f + __expf(2.f * aN));
        const float hv = (1.f - zz) * nn + zz * hold[e];
        hold[e] = hv;
        hh[e] = (_Float16)hv;
      }
      agstore_h4(hnx + (size_t)(g * 32 + eb) * HH + s * 32 + jq * 4, hh);
    }
    bar_arrive(ef, s, (unsigned)(t + 1));
  }

  // ---------------- D0: gi_dec = hT@dWih^T + dbih (-> Q), h0d = hT@fciW^T + fcib ----------------
  {
    bar_wait(ef, (unsigned)LL);  // hT ready
    const _Float16* hT = hbuf;   // parity: after 512 steps hT lives in buf0
    float4v acc[2][6];
    zero_acc(acc);
    #pragma unroll 1
    for (int ks = 0; ks < 8; ++ks) {
      const _Float16* ap = hT + (size_t)(g * 32 + l15) * HH + (w << 8) + ks * 32 + (lq << 3);
      half8 a0 = agload_h8(ap);
      half8 a1 = agload_h8(ap + 16 * HH);
      #pragma unroll
      for (int n = 0; n < 6; ++n) {
        const int row = (n >> 1) * 1024 + s * 32 + (n & 1) * 16 + l15;
        half8 bf = ld_w8_f16(dWih + (size_t)row * HH + (w << 8) + ks * 32 + (lq << 3));
        acc[0][n] = MFMA16(a0, bf, acc[0][n]);
        acc[1][n] = MFMA16(a1, bf, acc[1][n]);
      }
    }
    {
      float* Pw = P + w * 3104;
      #pragma unroll
      for (int m = 0; m < 2; ++m) {
        const int row0 = m * 16 + lq * 4;
        #pragma unroll
        for (int n = 0; n < 6; ++n) {
          const int col = (n >> 1) * 32 + (n & 1) * 16 + l15;
          #pragma unroll
          for (int r = 0; r < 4; ++r) Pw[(row0 + r) * 97 + col] = acc[m][n][r];
        }
      }
    }
    __syncthreads();
    #pragma unroll
    for (int e = 0; e < 4; ++e) {   // Q <- gi_dec (+ dbih), constant for all 24 steps
      const int j = jq * 4 + e;
      #pragma unroll
      for (int gate = 0; gate < 3; ++gate) {
        const int col = gate * 32 + j;
        Q[eb * 97 + col] = PS(eb, col) + dbih[gate * 1024 + s * 32 + j];
      }
    }
    __syncthreads();
    // h0d = hT @ fciW^T + fcib
    float4v acc2[2][2];
    zero_acc(acc2);
    #pragma unroll 1
    for (int ks = 0; ks < 8; ++ks) {
      const _Float16* ap = hT + (size_t)(g * 32 + l15) * HH + (w << 8) + ks * 32 + (lq << 3);
      half8 a0 = agload_h8(ap);
      half8 a1 = agload_h8(ap + 16 * HH);
      #pragma unroll
      for (int n2 = 0; n2 < 2; ++n2) {
        const int row = s * 32 + n2 * 16 + l15;
        half8 bf = ld_w8_f16(fciW + (size_t)row * HH + (w << 8) + ks * 32 + (lq << 3));
        acc2[0][n2] = MFMA16(a0, bf, acc2[0][n2]);
        acc2[1][n2] = MFMA16(a1, bf, acc2[1][n2]);
      }
    }
    {
      float* Pw = P + w * 3104;
      #pragma unroll
      for (int m = 0; m < 2; ++m) {
        const int row0 = m * 16 + lq * 4;
        #pragma unroll
        for (int n2 = 0; n2 < 2; ++n2) {
          const int col = n2 * 16 + l15;
          #pragma unroll
          for (int r = 0; r < 4; ++r) Pw[(row0 + r) * 97 + col] = acc2[m][n2][r];
        }
      }
    }
    __syncthreads();
    {
      half4v hh;
      #pragma unroll
      for (int e = 0; e < 4; ++e) {
        const int j = jq * 4 + e;
        const float v = PS(eb, j) + fcib[s * 32 + j];
        hold[e] = v;
        hh[e] = (_Float16)v;
      }
      // write h0d to buf1 (buf0 = hT still being read by group peers until barrier)
      agstore_h4(hbuf + (size_t)BB * HH + (size_t)(g * 32 + eb) * HH + s * 32 + jq * 4, hh);
    }
    bar_arrive(ef, s, (unsigned)(LL + 1));
  }

  // ---------------- decoder ----------------
  load_W_frags(dWhh, s, w, lane, BW);  // reuse register file
  float dbr_[4], dbz_[4], dbn_[4], fw0[4], fw1[4];
  #pragma unroll
  for (int e = 0; e < 4; ++e) {
    const int c = colb + e;
    dbr_[e] = dbhh[c];
    dbz_[e] = dbhh[1024 + c];
    dbn_[e] = dbhh[2048 + c];
    fw0[e] = fcW[c];           // fc_W [2][1024]
    fw1[e] = fcW[1024 + c];
  }
  #pragma unroll 1
  for (int t = 0; t < SS; ++t) {
    bar_wait(ef, (unsigned)(LL + 1 + t));
    const _Float16* hc = hbuf + (size_t)((t + 1) & 1) * BB * HH;  // t=0 reads buf1 (h0d)
    _Float16* hnx = hbuf + (size_t)(t & 1) * BB * HH;
    float4v acc[2][6];
    zero_acc(acc);
    #pragma unroll
    for (int ks = 0; ks < 8; ++ks) {
      const _Float16* ap = hc + (size_t)(g * 32 + l15) * HH + (w << 8) + ks * 32 + (lq << 3);
      half8 a0 = agload_h8(ap);
      half8 a1 = agload_h8(ap + 16 * HH);
      #pragma unroll
      for (int n = 0; n < 6; ++n) {
        acc[0][n] = MFMA16(a0, BW[n][ks], acc[0][n]);
        acc[1][n] = MFMA16(a1, BW[n][ks], acc[1][n]);
      }
    }
    {
      float* Pw = P + w * 3104;
      #pragma unroll
      for (int m = 0; m < 2; ++m) {
        const int row0 = m * 16 + lq * 4;
        #pragma unroll
        for (int n = 0; n < 6; ++n) {
          const int col = (n >> 1) * 32 + (n & 1) * 16 + l15;
          #pragma unroll
          for (int r = 0; r < 4; ++r) Pw[(row0 + r) * 97 + col] = acc[m][n][r];
        }
      }
    }
    __syncthreads();
    {
      half4v hh;
      float p0 = 0.f, p1 = 0.f;
      #pragma unroll
      for (int e = 0; e < 4; ++e) {
        const int j = jq * 4 + e;
        const float rr = 1.f / (1.f + __expf(-(PS(eb, j) + Q[eb * 97 + j] + dbr_[e])));
        const float zz = 1.f / (1.f + __expf(-(PS(eb, 32 + j) + Q[eb * 97 + 32 + j] + dbz_[e])));
        const float aN = Q[eb * 97 + 64 + j] + rr * (PS(eb, 64 + j) + dbn_[e]);
        const float nn = 1.f - 2.f / (1.f + __expf(2.f * aN));
        const float hv = (1.f - zz) * nn + zz * hold[e];
        hold[e] = hv;
        hh[e] = (_Float16)hv;
        p0 += hv * fw0[e];
        p1 += hv * fw1[e];
      }
      agstore_h4(hnx + (size_t)(g * 32 + eb) * HH + s * 32 + jq * 4, hh);
      // fc fused: reduce over this CU's 32 hidden cols (8 adjacent lanes share a batch row)
      p0 += __shfl_xor(p0, 1); p0 += __shfl_xor(p0, 2); p0 += __shfl_xor(p0, 4);
      p1 += __shfl_xor(p1, 1); p1 += __shfl_xor(p1, 2); p1 += __shfl_xor(p1, 4);
      if (jq == 0) {
        atomicAdd(&outp[((g * 32 + eb) * SS + t) * 2 + 0], p0);
        atomicAdd(&outp[((g * 32 + eb) * SS + t) * 2 + 1], p1);
      }
    }
    bar_arrive(ef, s, (unsigned)(LL + 2 + t));
  }

  // ---------------- grid barrier #2: group flag-barrier, then 8 leader RMWs ----------------
  bar_wait(ef, (unsigned)(LL + 1 + SS));   // group done (outp atomics drained pre-arrive)
  if (s == 0 && tid == 0) atomicAdd(gridbar, 1u);
  if (tid == 0) {
    while (agload_u32(gridbar) < 8u) __builtin_amdgcn_s_sleep(1);
  }
  __syncthreads();

  // ---------------- final: fc bias + two shifted de-smoothing passes ----------------
  if (blk < 2) {
    const int t5 = blk * 256 + tid;   // 512 threads: (b, c)
    const int b = t5 >> 1, c = t5 & 1;
    const float s2v = st12[b * 2 + c];
    const float s1v = st11[b * 2 + c];
    const float bias = fcb[c];
    float o0p = 0.f, o1p = 0.f;
    #pragma unroll 1
    for (int t = 0; t < SS; ++t) {
      const float o0 = outp[(b * SS + t) * 2 + c] + bias;
      const float o1 = 2.f * o0 - ((t == 0) ? s2v : o0p);              // (o0-0.5*st2)/0.5
      const float o2 = (o1 - 0.3f * ((t == 0) ? s1v : o1p)) * (1.f / 0.7f);
      o0p = o0; o1p = o1;
      out[b * 48 + t * 2 + c] = o2;
    }
  }

  // replay-safety: leave flags at 0 for the next launch (all blocks have passed
  // flag-barrier #1 before any block reaches here — guaranteed by grid barrier #2)
  if (tid == 0) agstore_u32(&flags[blk], 0u);
}

extern "C" void kernel_launch(void* const* d_in, const int* in_sizes, int n_in,
                              void* d_out, int out_size, void* d_ws, size_t ws_size,
                              hipStream_t stream) {
  (void)in_sizes; (void)n_in; (void)out_size; (void)ws_size;
  const float* x    = (const float*)d_in[0];
  const float* eWih = (const float*)d_in[1];
  const float* eWhh = (const float*)d_in[2];
  const float* ebih = (const float*)d_in[3];
  const float* ebhh = (const float*)d_in[4];
  const float* dWih = (const float*)d_in[5];
  const float* dWhh = (const float*)d_in[6];
  const float* dbih = (const float*)d_in[7];
  const float* dbhh = (const float*)d_in[8];
  const float* fciW = (const float*)d_in[9];
  const float* fcib = (const float*)d_in[10];
  const float* fcW  = (const float*)d_in[11];
  const float* fcb  = (const float*)d_in[12];
  float* out = (float*)d_out;
  char* ws = (char*)d_ws;

  ts_fused<<<dim3(256), dim3(256), 0, stream>>>(
      x, eWih, eWhh, ebih, ebhh, dWih, dWhh, dbih, dbhh,
      fciW, fcib, fcW, fcb, out, ws);
}